// Round 10
// baseline (113.432 us; speedup 1.0000x reference)
//
#include <hip/hip_runtime.h>

typedef __attribute__((ext_vector_type(8))) short short8;
typedef __attribute__((ext_vector_type(4))) float f32x4;

#define C_DIM 128
#define K_CODES 1024
#define TOT 8388608   // 16*128*64*64
#define NBLK 512      // 128 contiguous pixels per block

__device__ __forceinline__ unsigned int f2bf1(float f) {
  unsigned int u = __float_as_uint(f);
  return (u + 0x7FFFu + ((u >> 16) & 1u)) >> 16;   // RNE fp32->bf16
}
__device__ __forceinline__ unsigned int f2bf2(float lo, float hi) {
  return f2bf1(lo) | (f2bf1(hi) << 16);
}

union U16x8 { uint4 u; short8 s; };

// ---- P: bf16 codebook + (1 + ||e||^2) + zero used ----
// R8-proven (landed in the 113.3us run): vectorized convert + ||e||^2 via
// 32-lane shuffle butterfly over the same float4s (no uncoalesced re-read).
__global__ void prep_kernel(const float* __restrict__ cb,
                            unsigned short* __restrict__ ebf,
                            float* __restrict__ nsq1,
                            int* __restrict__ used) {
  int gid = blockIdx.x * 256 + threadIdx.x;     // 128 blocks * 256 = 32768 = K*C/4
  const float4 v = ((const float4*)cb)[gid];    // 32768*16B = 512KB = cb size
  uint2 pk;
  pk.x = f2bf2(v.x, v.y);
  pk.y = f2bf2(v.z, v.w);
  ((uint2*)ebf)[gid] = pk;                      // 32768*8B = 256KB = ebf size
  float s = v.x * v.x + v.y * v.y + v.z * v.z + v.w * v.w;
  #pragma unroll
  for (int m = 1; m <= 16; m <<= 1) s += __shfl_xor(s, m, 64);
  if ((threadIdx.x & 31) == 0)
    nsq1[gid >> 5] = 1.0f + s;   // +1 keeps d positive -> u32-monotone bits
  if (gid < K_CODES) used[gid] = 0;
}

// ---- M: R0-proven structure + ONLY the R6-verified LDS XOR swizzle ----
// R9 ledger: the swizzle (conflicts 2.1M cyc -> 0, verified R6) was never
// tested in isolation on the R0 geometry/epilogue — R6 bundled the kq-split
// (4x A redundancy), R7 bundled the algebraic-loss epilogue (write
// amplification). This build: byte-identical R0 phases except the staging
// write slots and B-read slots use the bijective swizzle
//   slot(r,g) = (r>>4)*256 + (g>>2)*64 + (r&15>>1)*8
//             + (((r^ (g>>2))&1)<<2) + (((g&3) ^ ((r&15)>>1))&3)
// (both-sides-or-neither, plain ds ops). Expected: BANK_CONFLICT -> ~0,
// vq -2..4us. K-loop is VALU/LDS-issue bound (R6: VALUBusy 2x MfmaUtil).
__global__ __launch_bounds__(256, 3)
void vq_main(const float* __restrict__ zin, const float* __restrict__ cb,
             const unsigned short* __restrict__ ebf,
             const float* __restrict__ nsq1,
             int* __restrict__ used, float* __restrict__ lossp,
             float* __restrict__ out) {
  __shared__ __align__(16) uint4 bG[2][1024];   // 2 x 16KB: 64-code chunks
  __shared__ float nsq_s[K_CODES];
  __shared__ unsigned int mergeK[128][2];
  __shared__ int   widx[128];
  __shared__ float wsum[4];

  const int t  = threadIdx.x;
  const int L  = t & 63;
  const int wv = t >> 6;        // wave 0..3
  const int ph = wv >> 1;       // pixel half: px [ph*64, ph*64+64)
  const int kh = wv & 1;        // code half: jj tiles {kh*2, kh*2+1}
  const int q  = L >> 4;        // lane quad
  const int nL = L & 15;

  const int bb = blockIdx.x >> 5;          // batch 0..15
  const int hg = blockIdx.x & 31;          // 128-px group
  const int zoff = bb * (C_DIM * 4096) + hg * 128;   // + c*4096 + p

  for (int i = t; i < K_CODES; i += 256) nsq_s[i] = nsq1[i];

  // ---- A fragments straight from global, packed bf16(-2z) in-register
  short8 afrag[16];
  #pragma unroll
  for (int mt = 0; mt < 4; ++mt) {
    const int wcol = ph * 64 + mt * 16 + nL;
    #pragma unroll
    for (int ks = 0; ks < 4; ++ks) {
      float v[8];
      #pragma unroll
      for (int u = 0; u < 8; ++u)
        v[u] = zin[zoff + (ks * 32 + q * 8 + u) * 4096 + wcol];
      U16x8 pk;
      pk.u.x = f2bf2(-2.f * v[0], -2.f * v[1]);
      pk.u.y = f2bf2(-2.f * v[2], -2.f * v[3]);
      pk.u.z = f2bf2(-2.f * v[4], -2.f * v[5]);
      pk.u.w = f2bf2(-2.f * v[6], -2.f * v[7]);
      afrag[mt * 4 + ks] = pk.s;
    }
  }

  // ---- staging thread roles (contiguous 1KB per wave-instruction), swizzled
  const uint4* __restrict__ ebv = (const uint4*)ebf;   // granule view, row=16
  const int nLw = t >> 4;        // row-within-group 0..15
  const int oct = t & 15;        // granule-within-row
  const int sks = oct >> 2, sq = oct & 3;
  const int swbase = (nLw >> 1) * 8 + (((nLw ^ sks) & 1) << 2)
                   + ((sq ^ (nLw >> 1)) & 3);

  // stage chunk 0
  #pragma unroll
  for (int p = 0; p < 4; ++p)
    bG[0][p * 256 + sks * 64 + swbase] = ebv[(p * 16 + nLw) * 16 + oct];
  __syncthreads();

  // read-side swizzled slot offsets (ks even -> sA, ks odd -> sB)
  const int rdq = (q ^ (nL >> 1)) & 3;
  const int sA = (nL >> 1) * 8 + ((nL & 1) << 2) + rdq;
  const int sB = (nL >> 1) * 8 + (((nL ^ 1) & 1) << 2) + rdq;

  unsigned int kmin[16];
  #pragma unroll
  for (int i = 0; i < 16; ++i) kmin[i] = 0xFFFFFFFFu;

  // ---- K loop: 16 chunks; this wave consumes its 2 jj-tiles (32 codes)
  #pragma unroll 1
  for (int ch = 0; ch < 16; ++ch) {
    const int cur = ch & 1;
    if (ch < 15) {                               // stage next chunk into !cur
      #pragma unroll
      for (int p = 0; p < 4; ++p)
        bG[cur ^ 1][p * 256 + sks * 64 + swbase] =
            ebv[((ch + 1) * 64 + p * 16 + nLw) * 16 + oct];
    }
    const short8* bp = (const short8*)bG[cur];
    #pragma unroll
    for (int j2 = 0; j2 < 2; ++j2) {
      const int jj = kh * 2 + j2;
      const int row = ch * 64 + jj * 16 + nL;    // this lane's code
      short8 b0 = bp[jj * 256 +   0 + sA];
      short8 b1 = bp[jj * 256 +  64 + sB];
      short8 b2 = bp[jj * 256 + 128 + sA];
      short8 b3 = bp[jj * 256 + 192 + sB];
      const float nv = nsq_s[row];
      f32x4 a0 = {nv, nv, nv, nv};
      f32x4 a1 = {nv, nv, nv, nv};
      f32x4 a2 = {nv, nv, nv, nv};
      f32x4 a3 = {nv, nv, nv, nv};
      a0 = __builtin_amdgcn_mfma_f32_16x16x32_bf16(afrag[0],  b0, a0, 0, 0, 0);
      a1 = __builtin_amdgcn_mfma_f32_16x16x32_bf16(afrag[4],  b0, a1, 0, 0, 0);
      a2 = __builtin_amdgcn_mfma_f32_16x16x32_bf16(afrag[8],  b0, a2, 0, 0, 0);
      a3 = __builtin_amdgcn_mfma_f32_16x16x32_bf16(afrag[12], b0, a3, 0, 0, 0);
      a0 = __builtin_amdgcn_mfma_f32_16x16x32_bf16(afrag[1],  b1, a0, 0, 0, 0);
      a1 = __builtin_amdgcn_mfma_f32_16x16x32_bf16(afrag[5],  b1, a1, 0, 0, 0);
      a2 = __builtin_amdgcn_mfma_f32_16x16x32_bf16(afrag[9],  b1, a2, 0, 0, 0);
      a3 = __builtin_amdgcn_mfma_f32_16x16x32_bf16(afrag[13], b1, a3, 0, 0, 0);
      a0 = __builtin_amdgcn_mfma_f32_16x16x32_bf16(afrag[2],  b2, a0, 0, 0, 0);
      a1 = __builtin_amdgcn_mfma_f32_16x16x32_bf16(afrag[6],  b2, a1, 0, 0, 0);
      a2 = __builtin_amdgcn_mfma_f32_16x16x32_bf16(afrag[10], b2, a2, 0, 0, 0);
      a3 = __builtin_amdgcn_mfma_f32_16x16x32_bf16(afrag[14], b2, a3, 0, 0, 0);
      a0 = __builtin_amdgcn_mfma_f32_16x16x32_bf16(afrag[3],  b3, a0, 0, 0, 0);
      a1 = __builtin_amdgcn_mfma_f32_16x16x32_bf16(afrag[7],  b3, a1, 0, 0, 0);
      a2 = __builtin_amdgcn_mfma_f32_16x16x32_bf16(afrag[11], b3, a2, 0, 0, 0);
      a3 = __builtin_amdgcn_mfma_f32_16x16x32_bf16(afrag[15], b3, a3, 0, 0, 0);
      const unsigned int rowc = (unsigned int)row;
      #pragma unroll
      for (int r = 0; r < 4; ++r) {
        unsigned int k0 = (__float_as_uint(a0[r]) & 0xFFFFFC00u) | rowc;
        if (k0 < kmin[r]) kmin[r] = k0;
        unsigned int k1 = (__float_as_uint(a1[r]) & 0xFFFFFC00u) | rowc;
        if (k1 < kmin[4 + r]) kmin[4 + r] = k1;
        unsigned int k2 = (__float_as_uint(a2[r]) & 0xFFFFFC00u) | rowc;
        if (k2 < kmin[8 + r]) kmin[8 + r] = k2;
        unsigned int k3 = (__float_as_uint(a3[r]) & 0xFFFFFC00u) | rowc;
        if (k3 < kmin[12 + r]) kmin[12 + r] = k3;
      }
    }
    __syncthreads();   // next-chunk writes visible; cur free for re-stage
  }

  // ---- in-wave butterfly u32-min over the 16 code-lanes of each quad
  #pragma unroll
  for (int m = 1; m <= 8; m <<= 1) {
    #pragma unroll
    for (int i = 0; i < 16; ++i) {
      unsigned int o = (unsigned int)__shfl_xor((int)kmin[i], m, 64);
      if (o < kmin[i]) kmin[i] = o;
    }
  }
  if (nL == 0) {
    #pragma unroll
    for (int mt = 0; mt < 4; ++mt)
      #pragma unroll
      for (int r = 0; r < 4; ++r)
        mergeK[ph * 64 + mt * 16 + q * 4 + r][kh] = kmin[mt * 4 + r];
  }
  __syncthreads();

  // ---- cross-half merge (2-way u32 min per pixel)
  if (t < 128) {
    unsigned int b = min(mergeK[t][0], mergeK[t][1]);
    int bi = (int)(b & 1023u);
    widx[t] = bi;
    used[bi] = 1;   // benign same-value race; kernel boundary = coherence
  }
  __syncthreads();

  // ---- gather bf16 e-row + coalesced z/out + loss partial (R0-proven)
  float lsum = 0.f;
  {
    const int p = t & 127, cg = t >> 7;    // 2 channel halves x 64 ch
    const int idx = widx[p];
    const uint4* erow = ebv + idx * 16 + cg * 8;
    const int obase = zoff + cg * 64 * 4096 + p;
    #pragma unroll 2
    for (int i = 0; i < 8; ++i) {
      uint4 g = erow[i];
      const unsigned int wrd[4] = {g.x, g.y, g.z, g.w};
      #pragma unroll
      for (int half = 0; half < 4; ++half) {
        float e0 = __uint_as_float(wrd[half] << 16);
        float e1 = __uint_as_float(wrd[half] & 0xFFFF0000u);
        int off = obase + (i * 8 + half * 2) * 4096;
        float d0 = zin[off] - e0;
        out[off] = e0;                     // lanes over p -> 256B contiguous
        lsum += d0 * d0;
        off += 4096;
        float d1 = zin[off] - e1;
        out[off] = e1;
        lsum += d1 * d1;
      }
    }
  }
  #pragma unroll
  for (int o = 32; o > 0; o >>= 1) lsum += __shfl_down(lsum, o, 64);
  if (L == 0) wsum[wv] = lsum;
  __syncthreads();
  if (t == 0) lossp[blockIdx.x] = wsum[0] + wsum[1] + wsum[2] + wsum[3];
}

// ---- F: usage count + loss finalize ----
__global__ void finalize_kernel(const int* __restrict__ used,
                                const float* __restrict__ lossp,
                                float* __restrict__ out2) {
  __shared__ int   redi[256];
  __shared__ float redf[256];
  int t = threadIdx.x;
  int s = 0;
  for (int i = t; i < K_CODES; i += 256) s += (used[i] != 0) ? 1 : 0;
  float ls = 0.f;
  for (int i = t; i < NBLK; i += 256) ls += lossp[i];
  redi[t] = s; redf[t] = ls;
  __syncthreads();
  for (int o = 128; o > 0; o >>= 1) {
    if (t < o) { redi[t] += redi[t + o]; redf[t] += redf[t + o]; }
    __syncthreads();
  }
  if (t == 0) {
    out2[0] = 1.25f * redf[0] / (float)TOT;  // (1+0.25)*MSE
    out2[1] = (float)redi[0] / 1024.0f;
  }
}

extern "C" void kernel_launch(void* const* d_in, const int* in_sizes, int n_in,
                              void* d_out, int out_size, void* d_ws, size_t ws_size,
                              hipStream_t stream) {
  const float* z  = (const float*)d_in[0];
  const float* cb = (const float*)d_in[1];
  float* out = (float*)d_out;
  char* ws = (char*)d_ws;
  unsigned short* ebf = (unsigned short*)ws;          // 262144 B
  float* nsq1  = (float*)(ws + 262144);               // 4096 B
  int*   used  = (int*)(ws + 266240);                 // 4096 B
  float* lossp = (float*)(ws + 270336);               // 2048 B (per-block partials)

  hipLaunchKernelGGL(prep_kernel, dim3(128), dim3(256), 0, stream,
                     cb, ebf, nsq1, used);
  hipLaunchKernelGGL(vq_main, dim3(NBLK), dim3(256), 0, stream,
                     z, cb, ebf, nsq1, used, lossp, out);
  hipLaunchKernelGGL(finalize_kernel, dim3(1), dim3(256), 0, stream,
                     used, lossp, out + TOT);
}